// Round 1
// baseline (1446.274 us; speedup 1.0000x reference)
//
#include <hip/hip_runtime.h>
#include <hip/hip_bf16.h>

#define N_    16
#define C_    64
#define J_    25
#define T_    128
#define L_    9
#define SIC   8
#define CH    9
#define OUT_  64
#define BTOT  (N_*J_*T_)      // 51200 streams
#define CNT   (N_*J_*T_*L_)   // 460800 positions
#define K1_BLOCKS (CNT/256)   // 1800

// ws float offsets
#define PART_OFF 0            // 1800*16 floats
#define SS_OFF   32768        // scale[8], shift[8]
#define WR_OFF   65536        // 9*64*112 = 64512 floats
#define Y_OFF    131072       // BTOT*72 = 3,686,400 floats
#define SPB      28
#define K3_THREADS 252        // 28 streams * 9 lanes

// ---------------- Kernel 1: 1x1 conv + ReLU + BN partial stats ----------------
__global__ __launch_bounds__(256) void k1_conv(
    const float* __restrict__ x, const float* __restrict__ cw,
    const float* __restrict__ cb, float* __restrict__ yws,
    float* __restrict__ part) {
  __shared__ float wl[SIC * C_];
  __shared__ float bl[SIC];
  __shared__ float wsum[4][16];
  int tid = threadIdx.x;
  wl[tid] = cw[tid];
  wl[tid + 256] = cw[tid + 256];
  if (tid < SIC) bl[tid] = cb[tid];
  __syncthreads();

  int pos = blockIdx.x * 256 + tid;     // < 460800
  int l  = pos % L_;
  int t  = (pos / L_) % T_;
  int jn = pos / (L_ * T_);             // n*J + j
  int n  = jn / J_;
  int j  = jn % J_;
  int base = ((n * C_) * J_ + j) * (T_ * L_) + t * L_ + l;
  const float* xp = x + base;

  float acc[SIC];
#pragma unroll
  for (int o = 0; o < SIC; o++) acc[o] = bl[o];
#pragma unroll 4
  for (int c = 0; c < C_; c++) {
    float xv = xp[c * (J_ * T_ * L_)];
#pragma unroll
    for (int o = 0; o < SIC; o++) acc[o] = fmaf(xv, wl[o * C_ + c], acc[o]);
  }
#pragma unroll
  for (int o = 0; o < SIC; o++) acc[o] = fmaxf(acc[o], 0.f);

  int b = jn * T_ + t;
  float4* dst = (float4*)(yws + (size_t)b * 72 + l * 8);
  dst[0] = make_float4(acc[0], acc[1], acc[2], acc[3]);
  dst[1] = make_float4(acc[4], acc[5], acc[6], acc[7]);

  // BN stats: per-channel sum and sumsq, block-reduced
  float vals[16];
#pragma unroll
  for (int o = 0; o < 8; o++) { vals[o] = acc[o]; vals[8 + o] = acc[o] * acc[o]; }
  int lane = tid & 63, wid = tid >> 6;
#pragma unroll
  for (int v = 0; v < 16; v++) {
    float s = vals[v];
    for (int off = 32; off > 0; off >>= 1) s += __shfl_down(s, off, 64);
    if (lane == 0) wsum[wid][v] = s;
  }
  __syncthreads();
  if (tid < 16)
    part[blockIdx.x * 16 + tid] = wsum[0][tid] + wsum[1][tid] + wsum[2][tid] + wsum[3][tid];
}

// ---------------- Kernel 2a: finalize BN scale/shift ----------------
__global__ __launch_bounds__(256) void k2_stats(
    const float* __restrict__ part, const float* __restrict__ gamma,
    const float* __restrict__ beta, float* __restrict__ ss) {
  __shared__ float red[16][16];
  int tid = threadIdx.x;
  int val = tid & 15, grp = tid >> 4;
  float s = 0.f;
  for (int blk = grp; blk < K1_BLOCKS; blk += 16) s += part[blk * 16 + val];
  red[grp][val] = s;
  __syncthreads();
  if (tid < 16) {
    float tot = 0.f;
#pragma unroll
    for (int g = 0; g < 16; g++) tot += red[g][tid];
    red[0][tid] = tot;   // same-wave lockstep: reads complete before writes
  }
  __syncthreads();
  if (tid < 8) {
    float mean = red[0][tid] * (1.f / CNT);
    float var  = red[0][8 + tid] * (1.f / CNT) - mean * mean;
    float sc = gamma[tid] * rsqrtf(var + 1e-5f);
    ss[tid] = sc;
    ss[8 + tid] = beta[tid] - mean * sc;
  }
}

// ---------------- Kernel 2b: rearrange lin_w into padded per-(i,o) slabs ----------------
// slab layout (112 floats, 16B-aligned rows): [0]=w1, [4..12]=w2 row (9), [16..96]=w3 slab (81)
__global__ __launch_bounds__(64) void k2_rearrange(
    const float* __restrict__ lw, float* __restrict__ wr) {
  int g = blockIdx.x * 64 + threadIdx.x;
  if (g >= 9 * 64) return;
  int i = g / 64, o = g % 64;
  float* d = wr + (size_t)(i * 64 + o) * 112;
  for (int q = 0; q < 112; q++) d[q] = 0.f;
  d[0] = lw[o * 819 + i];
  for (int j = 0; j < 9; j++) d[4 + j] = lw[o * 819 + 9 + i * 9 + j];
  for (int q = 0; q < 81; q++) d[16 + q] = lw[o * 819 + 90 + i * 81 + q];
}

// ---------------- Kernel 3: BN-affine + signature (9 lanes/stream) + fused linear ----------------
__global__ __launch_bounds__(K3_THREADS) void k3_sig(
    const float* __restrict__ yws, const float* __restrict__ wr,
    const float* __restrict__ lb, const float* __restrict__ ss,
    float* __restrict__ out) {
  __shared__ float ylds[SPB * 72];
  __shared__ float zacc[SPB * 64];
  __shared__ float ssl[16];
  int tid = threadIdx.x;
  if (tid < 16) ssl[tid] = ss[tid];
  int blockBase = blockIdx.x * SPB;
  int valid = BTOT - blockBase; if (valid > SPB) valid = SPB;
  __syncthreads();

  // Phase A: stage BN-affined stream points into LDS
  {
    int s = tid / 9, l = tid % 9;
    if (s < valid) {
      const float4* src = (const float4*)(yws + (size_t)(blockBase + s) * 72 + l * 8);
      float4 a = src[0], b = src[1];
      float* drow = ylds + tid * 8;
      drow[0] = fmaf(a.x, ssl[0], ssl[8]);
      drow[1] = fmaf(a.y, ssl[1], ssl[9]);
      drow[2] = fmaf(a.z, ssl[2], ssl[10]);
      drow[3] = fmaf(a.w, ssl[3], ssl[11]);
      drow[4] = fmaf(b.x, ssl[4], ssl[12]);
      drow[5] = fmaf(b.y, ssl[5], ssl[13]);
      drow[6] = fmaf(b.z, ssl[6], ssl[14]);
      drow[7] = fmaf(b.w, ssl[7], ssl[15]);
    }
  }
  __syncthreads();

  int s = tid / 9, i = tid % 9;
  bool act = (s < valid);
  float s1 = 0.f, s2[9], s3[81];
#pragma unroll
  for (int j = 0; j < 9; j++) s2[j] = 0.f;
#pragma unroll
  for (int q = 0; q < 81; q++) s3[q] = 0.f;
  const float* yrow = ylds + s * 72;

  // Phase B: depth-3 signature, slab i per lane.
  // step: a = 0.5*s1 + v_i/6 ; t_j = s2[j] + a*v[j] ; s3[j,k] += t_j*v[k]
  //       s2[j] += (s1 + 0.5*v_i)*v[j] ; s1 += v_i      (all with OLD s1/s2)
  if (act) {
#pragma unroll
    for (int l = 0; l < 9; l++) {
      float v[9];
      if (l == 0) {
        v[0] = 0.f;
#pragma unroll
        for (int c = 0; c < 8; c++) v[c + 1] = yrow[c];
      } else {
        v[0] = 0.125f;
#pragma unroll
        for (int c = 0; c < 8; c++) v[c + 1] = yrow[l * 8 + c] - yrow[(l - 1) * 8 + c];
      }
      float vi;
      if (i == 0) vi = v[0];
      else vi = (l == 0) ? yrow[i - 1]
                         : yrow[l * 8 + (i - 1)] - yrow[(l - 1) * 8 + (i - 1)];
      float a  = fmaf(vi, (1.f / 6.f), 0.5f * s1);
      float b2 = fmaf(vi, 0.5f, s1);
#pragma unroll
      for (int j = 0; j < 9; j++) {
        float tj = fmaf(a, v[j], s2[j]);
#pragma unroll
        for (int k = 0; k < 9; k++) s3[j * 9 + k] = fmaf(tj, v[k], s3[j * 9 + k]);
        s2[j] = fmaf(b2, v[j], s2[j]);
      }
      s1 += vi;
    }
  }

  // Phase C: fused linear projection (lane i dots its slab with w[o, slab i])
  for (int e = tid; e < valid * 64; e += K3_THREADS) zacc[e] = lb[e & 63];
  __syncthreads();
  if (act) {
    const float* wp0 = wr + (size_t)(i * 64) * 112;
#pragma unroll 1
    for (int o = 0; o < 64; o++) {
      const float* wp = wp0 + o * 112;
      float p = wp[0] * s1;
#pragma unroll
      for (int j = 0; j < 9; j++) p = fmaf(wp[4 + j], s2[j], p);
#pragma unroll
      for (int q = 0; q < 81; q++) p = fmaf(wp[16 + q], s3[q], p);
      atomicAdd(&zacc[s * 64 + o], p);
    }
  }
  __syncthreads();

  // write out [N, 64, J, T]
  for (int e = tid; e < valid * 64; e += K3_THREADS) {
    int sl = e >> 6, o = e & 63;
    int b = blockBase + sl;
    int t = b & (T_ - 1);
    int jn = b >> 7;
    int j = jn % J_, n = jn / J_;
    out[((n * OUT_ + o) * J_ + j) * T_ + t] = zacc[e];
  }
}

extern "C" void kernel_launch(void* const* d_in, const int* in_sizes, int n_in,
                              void* d_out, int out_size, void* d_ws, size_t ws_size,
                              hipStream_t stream) {
  const float* x     = (const float*)d_in[0];
  const float* cw    = (const float*)d_in[1];
  const float* cb    = (const float*)d_in[2];
  const float* gamma = (const float*)d_in[3];
  const float* beta  = (const float*)d_in[4];
  const float* lw    = (const float*)d_in[5];
  const float* lbias = (const float*)d_in[6];
  float* out = (float*)d_out;
  float* ws  = (float*)d_ws;
  if (ws_size < (size_t)(Y_OFF + BTOT * 72) * sizeof(float)) return;

  float* part = ws + PART_OFF;
  float* ss   = ws + SS_OFF;
  float* wr   = ws + WR_OFF;
  float* yws  = ws + Y_OFF;

  hipLaunchKernelGGL(k1_conv, dim3(K1_BLOCKS), dim3(256), 0, stream, x, cw, cb, yws, part);
  hipLaunchKernelGGL(k2_stats, dim3(1), dim3(256), 0, stream, part, gamma, beta, ss);
  hipLaunchKernelGGL(k2_rearrange, dim3(9), dim3(64), 0, stream, lw, wr);
  int nblk = (BTOT + SPB - 1) / SPB;
  hipLaunchKernelGGL(k3_sig, dim3(nblk), dim3(K3_THREADS), 0, stream, yws, wr, lbias, ss, out);
}

// Round 2
// 124.626 us; speedup vs baseline: 11.6049x; 11.6049x over previous
//
#include <hip/hip_runtime.h>
#include <hip/hip_bf16.h>

typedef unsigned short u16;
typedef __attribute__((ext_vector_type(8))) short short8;
typedef __attribute__((ext_vector_type(4))) float f32x4;

#define N_    16
#define C_    64
#define J_    25
#define T_    128
#define L_    9
#define SIC   8
#define OUT_  64
#define BTOT  (N_*J_*T_)      // 51200 streams
#define MHALF (BTOT/2)        // 25600
#define CNT   (BTOT*L_)       // 460800 positions
#define K1_BLOCKS (CNT/256)   // 1800
#define KPAD  832             // 819 padded to 13*64

// ws float offsets
#define PART_OFF 0
#define SS_OFF   32768
#define BT_OFF   40960        // 64*832 u16 = 26624 floats
#define Y_OFF    69632        // BTOT*72 floats
#define A_OFF    3801088      // MHALF*832 u16 = 10,649,600 floats
#define WS_NEED  ((size_t)14450688 * 4)

#define SPB      28
#define K3A_THREADS 252

#define GLOAD16(gp, lp) \
  __builtin_amdgcn_global_load_lds((const __attribute__((address_space(1))) unsigned int*)(gp), \
                                   (__attribute__((address_space(3))) unsigned int*)(lp), 16, 0, 0)

// ---------------- Kernel 1: 1x1 conv + ReLU + BN partial stats ----------------
__global__ __launch_bounds__(256) void k1_conv(
    const float* __restrict__ x, const float* __restrict__ cw,
    const float* __restrict__ cb, float* __restrict__ yws,
    float* __restrict__ part) {
  __shared__ float wl[SIC * C_];
  __shared__ float bl[SIC];
  __shared__ float wsum[4][16];
  int tid = threadIdx.x;
  wl[tid] = cw[tid];
  wl[tid + 256] = cw[tid + 256];
  if (tid < SIC) bl[tid] = cb[tid];
  __syncthreads();

  int pos = blockIdx.x * 256 + tid;
  int l  = pos % L_;
  int t  = (pos / L_) % T_;
  int jn = pos / (L_ * T_);
  int n  = jn / J_;
  int j  = jn % J_;
  int base = ((n * C_) * J_ + j) * (T_ * L_) + t * L_ + l;
  const float* xp = x + base;

  float acc[SIC];
#pragma unroll
  for (int o = 0; o < SIC; o++) acc[o] = bl[o];
#pragma unroll 4
  for (int c = 0; c < C_; c++) {
    float xv = xp[c * (J_ * T_ * L_)];
#pragma unroll
    for (int o = 0; o < SIC; o++) acc[o] = fmaf(xv, wl[o * C_ + c], acc[o]);
  }
#pragma unroll
  for (int o = 0; o < SIC; o++) acc[o] = fmaxf(acc[o], 0.f);

  int b = jn * T_ + t;
  float4* dst = (float4*)(yws + (size_t)b * 72 + l * 8);
  dst[0] = make_float4(acc[0], acc[1], acc[2], acc[3]);
  dst[1] = make_float4(acc[4], acc[5], acc[6], acc[7]);

  float vals[16];
#pragma unroll
  for (int o = 0; o < 8; o++) { vals[o] = acc[o]; vals[8 + o] = acc[o] * acc[o]; }
  int lane = tid & 63, wid = tid >> 6;
#pragma unroll
  for (int v = 0; v < 16; v++) {
    float s = vals[v];
    for (int off = 32; off > 0; off >>= 1) s += __shfl_down(s, off, 64);
    if (lane == 0) wsum[wid][v] = s;
  }
  __syncthreads();
  if (tid < 16)
    part[blockIdx.x * 16 + tid] = wsum[0][tid] + wsum[1][tid] + wsum[2][tid] + wsum[3][tid];
}

// ---------------- Kernel 2a: finalize BN scale/shift ----------------
__global__ __launch_bounds__(256) void k2_stats(
    const float* __restrict__ part, const float* __restrict__ gamma,
    const float* __restrict__ beta, float* __restrict__ ss) {
  __shared__ float red[16][16];
  int tid = threadIdx.x;
  int val = tid & 15, grp = tid >> 4;
  float s = 0.f;
  for (int blk = grp; blk < K1_BLOCKS; blk += 16) s += part[blk * 16 + val];
  red[grp][val] = s;
  __syncthreads();
  if (tid < 16) {
    float tot = 0.f;
#pragma unroll
    for (int g = 0; g < 16; g++) tot += red[g][tid];
    red[0][tid] = tot;
  }
  __syncthreads();
  if (tid < 8) {
    float mean = red[0][tid] * (1.f / CNT);
    float var  = red[0][8 + tid] * (1.f / CNT) - mean * mean;
    float sc = gamma[tid] * rsqrtf(var + 1e-5f);
    ss[tid] = sc;
    ss[8 + tid] = beta[tid] - mean * sc;
  }
}

// ---------------- Kernel 2b: lin_w -> Bt bf16 [64][832] (rows>=819 zero) ----------------
__global__ __launch_bounds__(256) void k2_bt(
    const float* __restrict__ lw, u16* __restrict__ Bt) {
  int idx = blockIdx.x * 256 + threadIdx.x;
  if (idx >= OUT_ * KPAD) return;
  int o = idx / KPAD, k = idx % KPAD;
  float v = (k < 819) ? lw[o * 819 + k] : 0.f;
  __hip_bfloat16 h = __float2bfloat16(v);
  Bt[idx] = *reinterpret_cast<u16*>(&h);
}

// ---------------- Kernel 3a: BN-affine + signature -> A bf16 [MHALF][832] ----------------
__global__ __launch_bounds__(K3A_THREADS, 2) void k3a_sig(
    const float* __restrict__ yws, const float* __restrict__ ss,
    u16* __restrict__ A, int half) {
  __shared__ __align__(16) float ylds[SPB * 72];
  __shared__ __align__(16) u16 sig_lds[SPB][KPAD];
  __shared__ float ssl[16];
  int tid = threadIdx.x;
  if (tid < 16) ssl[tid] = ss[tid];
  int localBase = blockIdx.x * SPB;
  int valid = MHALF - localBase; if (valid > SPB) valid = SPB;
  int gBase = half * MHALF + localBase;
  __syncthreads();

  // Phase A: stage BN-affined stream points into LDS
  {
    int s = tid / 9, l = tid % 9;
    if (s < valid) {
      const float4* src = (const float4*)(yws + (size_t)(gBase + s) * 72 + l * 8);
      float4 a = src[0], b = src[1];
      float* drow = ylds + tid * 8;
      drow[0] = fmaf(a.x, ssl[0], ssl[8]);
      drow[1] = fmaf(a.y, ssl[1], ssl[9]);
      drow[2] = fmaf(a.z, ssl[2], ssl[10]);
      drow[3] = fmaf(a.w, ssl[3], ssl[11]);
      drow[4] = fmaf(b.x, ssl[4], ssl[12]);
      drow[5] = fmaf(b.y, ssl[5], ssl[13]);
      drow[6] = fmaf(b.z, ssl[6], ssl[14]);
      drow[7] = fmaf(b.w, ssl[7], ssl[15]);
    }
  }
  __syncthreads();

  int s = tid / 9, i = tid % 9;
  bool act = (s < valid);
  float s1 = 0.f, s2[9], s3[81];
#pragma unroll
  for (int j = 0; j < 9; j++) s2[j] = 0.f;
#pragma unroll
  for (int q = 0; q < 81; q++) s3[q] = 0.f;
  const float* yrow = ylds + s * 72;

  if (act) {
#pragma unroll
    for (int l = 0; l < 9; l++) {
      float v[9];
      if (l == 0) {
        v[0] = 0.f;
#pragma unroll
        for (int c = 0; c < 8; c++) v[c + 1] = yrow[c];
      } else {
        v[0] = 0.125f;
#pragma unroll
        for (int c = 0; c < 8; c++) v[c + 1] = yrow[l * 8 + c] - yrow[(l - 1) * 8 + c];
      }
      float vi;
      if (i == 0) vi = v[0];
      else vi = (l == 0) ? yrow[i - 1]
                         : yrow[l * 8 + (i - 1)] - yrow[(l - 1) * 8 + (i - 1)];
      float a  = fmaf(vi, (1.f / 6.f), 0.5f * s1);
      float b2 = fmaf(vi, 0.5f, s1);
#pragma unroll
      for (int j = 0; j < 9; j++) {
        float tj = fmaf(a, v[j], s2[j]);
#pragma unroll
        for (int k = 0; k < 9; k++) s3[j * 9 + k] = fmaf(tj, v[k], s3[j * 9 + k]);
        s2[j] = fmaf(b2, v[j], s2[j]);
      }
      s1 += vi;
    }
  }

  // write lane slab into sig_lds (bf16)
  if (act) {
    u16* row = sig_lds[s];
    __hip_bfloat16 h;
    h = __float2bfloat16(s1); row[i] = *reinterpret_cast<u16*>(&h);
#pragma unroll
    for (int j = 0; j < 9; j++) {
      h = __float2bfloat16(s2[j]); row[9 + i * 9 + j] = *reinterpret_cast<u16*>(&h);
    }
#pragma unroll
    for (int q = 0; q < 81; q++) {
      h = __float2bfloat16(s3[q]); row[90 + i * 81 + q] = *reinterpret_cast<u16*>(&h);
    }
    if (i == 0) {
#pragma unroll
      for (int c = 819; c < KPAD; c++) row[c] = 0;
    }
  }
  __syncthreads();

  // coalesced writeout: valid*104 16B chunks
  int nch = valid * 104;
  for (int e = tid; e < nch; e += K3A_THREADS) {
    int sr = e / 104, c = e % 104;
    float4 v = *(const float4*)((const char*)sig_lds + (size_t)sr * 1664 + c * 16);
    *(float4*)((char*)A + (size_t)(localBase + sr) * 1664 + c * 16) = v;
  }
}

// ---------------- Kernel 3b: GEMM A[MHALF x 832]bf16 * Bt[64 x 832]bf16 -> out ----------------
__global__ __launch_bounds__(256, 2) void k3b_gemm(
    const u16* __restrict__ A, const u16* __restrict__ Bt,
    const float* __restrict__ lb, float* __restrict__ out, int half) {
  __shared__ __align__(16) u16 ab[2][8192];  // per buf: [0..4095]=A 64x64, [4096..8191]=B 64x64
  int tid = threadIdx.x;
  int mBase = blockIdx.x * 64;
  int w = tid >> 6, l = tid & 63;
  int wavebase = tid & ~63;

  f32x4 acc[4] = {f32x4{0,0,0,0}, f32x4{0,0,0,0}, f32x4{0,0,0,0}, f32x4{0,0,0,0}};

  // stage K-tile kt into buffer bufi
#define STAGE(kt, bufi) do { \
    _Pragma("unroll") \
    for (int r = 0; r < 2; ++r) { \
      int q = r * 256 + tid; \
      int row = q >> 3, dslot = (q & 7) ^ (row & 7); \
      const u16* srcA = A + (size_t)(mBase + row) * KPAD + (kt) * 64 + dslot * 8; \
      GLOAD16(srcA, &ab[bufi][(size_t)(r * 256 + wavebase) * 8]); \
    } \
    _Pragma("unroll") \
    for (int r = 0; r < 2; ++r) { \
      int q = r * 256 + tid; \
      int row = q >> 3, dslot = (q & 7) ^ (row & 7); \
      const u16* srcB = Bt + (size_t)row * KPAD + (kt) * 64 + dslot * 8; \
      GLOAD16(srcB, &ab[bufi][4096 + (size_t)(r * 256 + wavebase) * 8]); \
    } \
  } while (0)

  STAGE(0, 0);
  __syncthreads();
#pragma unroll 1
  for (int kt = 0; kt < 13; ++kt) {
    int buf = kt & 1;
    if (kt + 1 < 13) STAGE(kt + 1, buf ^ 1);
    const u16* ap = ab[buf];
    const u16* bp = ab[buf] + 4096;
#pragma unroll
    for (int s = 0; s < 2; ++s) {
      int arow = w * 16 + (l & 15);
      int aslot = (s * 4 + (l >> 4)) ^ (arow & 7);
      short8 af = *(const short8*)&ap[arow * 64 + aslot * 8];
#pragma unroll
      for (int nf = 0; nf < 4; ++nf) {
        int brow = nf * 16 + (l & 15);
        int bslot = (s * 4 + (l >> 4)) ^ (brow & 7);
        short8 bfr = *(const short8*)&bp[brow * 64 + bslot * 8];
        acc[nf] = __builtin_amdgcn_mfma_f32_16x16x32_bf16(af, bfr, acc[nf], 0, 0, 0);
      }
    }
    __syncthreads();
  }

  // epilogue: transpose through LDS (row pad 65 to kill bank conflicts), coalesced out
  float* c_lds = (float*)&ab[0][0];  // 64*65 floats = 16.6KB, fits in 32KB
#pragma unroll
  for (int nf = 0; nf < 4; ++nf) {
#pragma unroll
    for (int r = 0; r < 4; ++r) {
      int o = nf * 16 + (l & 15);
      int m = w * 16 + (l >> 4) * 4 + r;
      c_lds[o * 65 + m] = acc[nf][r];
    }
  }
  __syncthreads();
  int b0 = half * MHALF + mBase;
  int n = b0 / (J_ * T_), j = (b0 >> 7) % J_, t0 = b0 & (T_ - 1);
#pragma unroll 4
  for (int rep = 0; rep < 16; ++rep) {
    int idx = rep * 256 + tid;
    int o = idx >> 6, tl = idx & 63;
    out[(((size_t)n * OUT_ + o) * J_ + j) * T_ + t0 + tl] = c_lds[o * 65 + tl] + lb[o];
  }
#undef STAGE
}

extern "C" void kernel_launch(void* const* d_in, const int* in_sizes, int n_in,
                              void* d_out, int out_size, void* d_ws, size_t ws_size,
                              hipStream_t stream) {
  const float* x     = (const float*)d_in[0];
  const float* cw    = (const float*)d_in[1];
  const float* cb    = (const float*)d_in[2];
  const float* gamma = (const float*)d_in[3];
  const float* beta  = (const float*)d_in[4];
  const float* lw    = (const float*)d_in[5];
  const float* lbias = (const float*)d_in[6];
  float* out = (float*)d_out;
  float* ws  = (float*)d_ws;
  if (ws_size < WS_NEED) return;

  float* part = ws + PART_OFF;
  float* ss   = ws + SS_OFF;
  u16*   bt   = (u16*)(ws + BT_OFF);
  float* yws  = ws + Y_OFF;
  u16*   amat = (u16*)(ws + A_OFF);

  hipLaunchKernelGGL(k1_conv, dim3(K1_BLOCKS), dim3(256), 0, stream, x, cw, cb, yws, part);
  hipLaunchKernelGGL(k2_stats, dim3(1), dim3(256), 0, stream, part, gamma, beta, ss);
  hipLaunchKernelGGL(k2_bt, dim3((OUT_ * KPAD + 255) / 256), dim3(256), 0, stream, lw, bt);

  int nblk3a = (MHALF + SPB - 1) / SPB;   // 915
  int nblk3b = MHALF / 64;                // 400
  for (int h = 0; h < 2; ++h) {
    hipLaunchKernelGGL(k3a_sig, dim3(nblk3a), dim3(K3A_THREADS), 0, stream, yws, ss, amat, h);
    hipLaunchKernelGGL(k3b_gemm, dim3(nblk3b), dim3(256), 0, stream, amat, bt, lbias, out, h);
  }
}

// Round 4
// 109.536 us; speedup vs baseline: 13.2037x; 1.1378x over previous
//
#include <hip/hip_runtime.h>
#include <hip/hip_bf16.h>

typedef unsigned short u16;
typedef __attribute__((ext_vector_type(8))) short short8;
typedef __attribute__((ext_vector_type(4))) float f32x4;

#define N_    16
#define C_    64
#define J_    25
#define T_    128
#define L_    9
#define SIC   8
#define OUT_  64
#define BTOT  (N_*J_*T_)      // 51200 streams
#define CNT   (BTOT*L_)       // 460800 positions
#define K1_BLOCKS (CNT/256)   // 1800
#define KPAD  896             // 9 slabs * 96 + 32 pad; 28 K-steps of 32
#define SPB   28              // streams per block (M-tile 32, rows 28..31 zero)

// ws float offsets
#define PART_OFF 0
#define SS_OFF   32768
#define BT_OFF   40960        // 64*896 u16 = 28672 floats
#define Y_OFF    69632        // BTOT*72 floats
#define WS_NEED  ((size_t)(Y_OFF + BTOT*72) * 4)

__device__ __forceinline__ short to_bf16(float x) {
  union { __hip_bfloat16 h; u16 u; } cv;
  cv.h = __float2bfloat16(x);
  return (short)cv.u;
}

// ---------------- Kernel 1: 1x1 conv + ReLU + BN partial stats ----------------
__global__ __launch_bounds__(256) void k1_conv(
    const float* __restrict__ x, const float* __restrict__ cw,
    const float* __restrict__ cb, float* __restrict__ yws,
    float* __restrict__ part) {
  __shared__ float wl[SIC * C_];
  __shared__ float bl[SIC];
  __shared__ float wsum[4][16];
  int tid = threadIdx.x;
  wl[tid] = cw[tid];
  wl[tid + 256] = cw[tid + 256];
  if (tid < SIC) bl[tid] = cb[tid];
  __syncthreads();

  int pos = blockIdx.x * 256 + tid;
  int l  = pos % L_;
  int t  = (pos / L_) % T_;
  int jn = pos / (L_ * T_);
  int n  = jn / J_;
  int j  = jn % J_;
  int base = ((n * C_) * J_ + j) * (T_ * L_) + t * L_ + l;
  const float* xp = x + base;

  float acc[SIC];
#pragma unroll
  for (int o = 0; o < SIC; o++) acc[o] = bl[o];
#pragma unroll 4
  for (int c = 0; c < C_; c++) {
    float xv = xp[c * (J_ * T_ * L_)];
#pragma unroll
    for (int o = 0; o < SIC; o++) acc[o] = fmaf(xv, wl[o * C_ + c], acc[o]);
  }
#pragma unroll
  for (int o = 0; o < SIC; o++) acc[o] = fmaxf(acc[o], 0.f);

  int b = jn * T_ + t;
  float4* dst = (float4*)(yws + (size_t)b * 72 + l * 8);
  dst[0] = make_float4(acc[0], acc[1], acc[2], acc[3]);
  dst[1] = make_float4(acc[4], acc[5], acc[6], acc[7]);

  float vals[16];
#pragma unroll
  for (int o = 0; o < 8; o++) { vals[o] = acc[o]; vals[8 + o] = acc[o] * acc[o]; }
  int lane = tid & 63, wid = tid >> 6;
#pragma unroll
  for (int v = 0; v < 16; v++) {
    float s = vals[v];
    for (int off = 32; off > 0; off >>= 1) s += __shfl_down(s, off, 64);
    if (lane == 0) wsum[wid][v] = s;
  }
  __syncthreads();
  if (tid < 16)
    part[blockIdx.x * 16 + tid] = wsum[0][tid] + wsum[1][tid] + wsum[2][tid] + wsum[3][tid];
}

// ---------------- Kernel 2a: finalize BN scale/shift ----------------
__global__ __launch_bounds__(256) void k2_stats(
    const float* __restrict__ part, const float* __restrict__ gamma,
    const float* __restrict__ beta, float* __restrict__ ss) {
  __shared__ float red[16][16];
  int tid = threadIdx.x;
  int val = tid & 15, grp = tid >> 4;
  float s = 0.f;
  for (int blk = grp; blk < K1_BLOCKS; blk += 16) s += part[blk * 16 + val];
  red[grp][val] = s;
  __syncthreads();
  if (tid < 16) {
    float tot = 0.f;
#pragma unroll
    for (int g = 0; g < 16; g++) tot += red[g][tid];
    red[0][tid] = tot;
  }
  __syncthreads();
  if (tid < 8) {
    float mean = red[0][tid] * (1.f / CNT);
    float var  = red[0][8 + tid] * (1.f / CNT) - mean * mean;
    float sc = gamma[tid] * rsqrtf(var + 1e-5f);
    ss[tid] = sc;
    ss[8 + tid] = beta[tid] - mean * sc;
  }
}

// ---------------- Kernel 2b: lin_w -> Bt bf16 [64][896], K-permuted slab layout ----
// k' = i*96 + p : p=0 -> level1[i]; p in [1,10) -> level2[9 + i*9 + p-1];
//                 p in [10,91) -> level3[90 + i*81 + p-10]; else 0. k'>=864 -> 0.
__global__ __launch_bounds__(256) void k2_bt(
    const float* __restrict__ lw, u16* __restrict__ Bt) {
  int idx = blockIdx.x * 256 + threadIdx.x;
  if (idx >= OUT_ * KPAD) return;
  int o = idx / KPAD, k = idx % KPAD;
  float v = 0.f;
  if (k < 864) {
    int i = k / 96, p = k % 96;
    if (p < 91) {
      int orig = (p == 0) ? i : (p < 10 ? 9 + i * 9 + (p - 1) : 90 + i * 81 + (p - 10));
      v = lw[o * 819 + orig];
    }
  }
  Bt[idx] = (u16)to_bf16(v);
}

// ---------------- Kernel 3: fused BN-affine + signature + GEMM ----------------
__global__ __launch_bounds__(256, 2) void k3_fused(
    const float* __restrict__ yws, const float* __restrict__ ss,
    const u16* __restrict__ Bt, const float* __restrict__ lb,
    float* __restrict__ out) {
  __shared__ __align__(16) u16 sig_lds[32 * KPAD];   // 57,344 B
  __shared__ float ssl[16];
  int tid = threadIdx.x;
  if (tid < 16) ssl[tid] = ss[tid];
  int gBase = blockIdx.x * SPB;
  int valid = BTOT - gBase; if (valid > SPB) valid = SPB;
  __syncthreads();

  // ----- Phase 1: signature (9 lanes per stream), y streamed from global -----
  {
    int s = tid / 9, i = tid % 9;
    bool act = (s < valid);
    if (act) {
      const float4* yp = (const float4*)(yws + (size_t)(gBase + s) * 72);
      float s1 = 0.f, s2[9], s3[81];
#pragma unroll
      for (int j = 0; j < 9; j++) s2[j] = 0.f;
#pragma unroll
      for (int q = 0; q < 81; q++) s3[q] = 0.f;

      float prev[8];
#pragma unroll
      for (int l = 0; l < 9; l++) {
        float4 a = yp[l * 2], b4 = yp[l * 2 + 1];
        float cur[8];
        cur[0] = fmaf(a.x,  ssl[0], ssl[8]);
        cur[1] = fmaf(a.y,  ssl[1], ssl[9]);
        cur[2] = fmaf(a.z,  ssl[2], ssl[10]);
        cur[3] = fmaf(a.w,  ssl[3], ssl[11]);
        cur[4] = fmaf(b4.x, ssl[4], ssl[12]);
        cur[5] = fmaf(b4.y, ssl[5], ssl[13]);
        cur[6] = fmaf(b4.z, ssl[6], ssl[14]);
        cur[7] = fmaf(b4.w, ssl[7], ssl[15]);
        float v[9];
        if (l == 0) {
          v[0] = 0.f;
#pragma unroll
          for (int c = 0; c < 8; c++) v[c + 1] = cur[c];
        } else {
          v[0] = 0.125f;
#pragma unroll
          for (int c = 0; c < 8; c++) v[c + 1] = cur[c] - prev[c];
        }
        // vi = v[i] without dynamic register indexing (rule #20)
        float vi = v[8];
#pragma unroll
        for (int k = 7; k >= 0; k--) vi = (i == k) ? v[k] : vi;

        float aa = fmaf(vi, (1.f / 6.f), 0.5f * s1);
        float b2 = fmaf(vi, 0.5f, s1);
#pragma unroll
        for (int j = 0; j < 9; j++) {
          float tj = fmaf(aa, v[j], s2[j]);
#pragma unroll
          for (int k = 0; k < 9; k++) s3[j * 9 + k] = fmaf(tj, v[k], s3[j * 9 + k]);
          s2[j] = fmaf(b2, v[j], s2[j]);
        }
        s1 += vi;
#pragma unroll
        for (int c = 0; c < 8; c++) prev[c] = cur[c];
      }

      // emit slab as 12 swizzled ds_write_b128 (slot' = slot ^ (s&7))
      u16* rowbase = sig_lds + s * KPAD;
      int sw = s & 7;
      {
        short8 ch;
        ch[0] = to_bf16(s1);
#pragma unroll
        for (int w = 0; w < 7; w++) ch[w + 1] = to_bf16(s2[w]);
        *(short8*)&rowbase[(((i * 12 + 0) ^ sw) * 8)] = ch;
      }
      {
        short8 ch;
        ch[0] = to_bf16(s2[7]); ch[1] = to_bf16(s2[8]);
#pragma unroll
        for (int w = 0; w < 6; w++) ch[w + 2] = to_bf16(s3[w]);
        *(short8*)&rowbase[(((i * 12 + 1) ^ sw) * 8)] = ch;
      }
#pragma unroll
      for (int c = 2; c <= 10; c++) {
        short8 ch;
#pragma unroll
        for (int w = 0; w < 8; w++) ch[w] = to_bf16(s3[c * 8 - 10 + w]);
        *(short8*)&rowbase[(((i * 12 + c) ^ sw) * 8)] = ch;
      }
      {
        short8 ch;
        ch[0] = to_bf16(s3[78]); ch[1] = to_bf16(s3[79]); ch[2] = to_bf16(s3[80]);
        ch[3] = 0; ch[4] = 0; ch[5] = 0; ch[6] = 0; ch[7] = 0;
        *(short8*)&rowbase[(((i * 12 + 11) ^ sw) * 8)] = ch;
      }
      // FIX (round-3 NaN): logical chunks 108..111 were never written, but the
      // GEMM reads all 112 chunks/row -> uninit LDS (x0 in B, but NaN*0=NaN).
      // Lanes i<4 write the zero chunk at the same XOR-transformed slot.
      if (i < 4) {
        short8 z = {0, 0, 0, 0, 0, 0, 0, 0};
        *(short8*)&rowbase[(((108 + i) ^ sw) * 8)] = z;
      }
    }
  }
  // zero pad rows [valid, 32)
  {
    short8 z = {0, 0, 0, 0, 0, 0, 0, 0};
    int padChunks = (32 - valid) * 112;
    for (int e = tid; e < padChunks; e += 256) {
      int r = valid + e / 112, sl = e % 112;
      *(short8*)&sig_lds[r * KPAD + sl * 8] = z;
    }
  }
  __syncthreads();

  // ----- Phase 2: GEMM M=32 x N=64 x K=896 -----
  int w = tid >> 6, l = tid & 63;
  int brow = (w << 4) + (l & 15);
  const short8* bp = (const short8*)(Bt + (size_t)brow * KPAD);
  int arow0 = (l & 15), arow1 = 16 + (l & 15);
  int asw = arow0 & 7;  // same for arow1
  f32x4 acc0 = {0, 0, 0, 0}, acc1 = {0, 0, 0, 0};
#pragma unroll
  for (int ks = 0; ks < 28; ks++) {
    int s4 = ks * 4 + (l >> 4);
    short8 bfrag = bp[s4];
    short8 a0 = *(const short8*)&sig_lds[arow0 * KPAD + ((s4 ^ asw) * 8)];
    short8 a1 = *(const short8*)&sig_lds[arow1 * KPAD + ((s4 ^ asw) * 8)];
    acc0 = __builtin_amdgcn_mfma_f32_16x16x32_bf16(a0, bfrag, acc0, 0, 0, 0);
    acc1 = __builtin_amdgcn_mfma_f32_16x16x32_bf16(a1, bfrag, acc1, 0, 0, 0);
  }
  __syncthreads();

  // ----- Epilogue: transpose via LDS (stride 33), coalesced writeout -----
  float* c_lds = (float*)sig_lds;  // 64*33*4 = 8448 B, reuse
  int o = (w << 4) + (l & 15);
#pragma unroll
  for (int r = 0; r < 4; r++) {
    int m0 = (l >> 4) * 4 + r;
    c_lds[o * 33 + m0] = acc0[r];
    c_lds[o * 33 + 16 + m0] = acc1[r];
  }
  __syncthreads();
  for (int e = tid; e < 2048; e += 256) {
    int o2 = e >> 5, m = e & 31;
    if (m < valid) {
      int b = gBase + m;
      int n = b / (J_ * T_), rem = b % (J_ * T_);
      int j = rem >> 7, t = rem & (T_ - 1);
      out[(((size_t)n * OUT_ + o2) * J_ + j) * T_ + t] = c_lds[o2 * 33 + m] + lb[o2];
    }
  }
}

extern "C" void kernel_launch(void* const* d_in, const int* in_sizes, int n_in,
                              void* d_out, int out_size, void* d_ws, size_t ws_size,
                              hipStream_t stream) {
  const float* x     = (const float*)d_in[0];
  const float* cw    = (const float*)d_in[1];
  const float* cb    = (const float*)d_in[2];
  const float* gamma = (const float*)d_in[3];
  const float* beta  = (const float*)d_in[4];
  const float* lw    = (const float*)d_in[5];
  const float* lbias = (const float*)d_in[6];
  float* out = (float*)d_out;
  float* ws  = (float*)d_ws;
  if (ws_size < WS_NEED) return;

  float* part = ws + PART_OFF;
  float* ss   = ws + SS_OFF;
  u16*   bt   = (u16*)(ws + BT_OFF);
  float* yws  = ws + Y_OFF;

  hipLaunchKernelGGL(k1_conv, dim3(K1_BLOCKS), dim3(256), 0, stream, x, cw, cb, yws, part);
  hipLaunchKernelGGL(k2_stats, dim3(1), dim3(256), 0, stream, part, gamma, beta, ss);
  hipLaunchKernelGGL(k2_bt, dim3((OUT_ * KPAD + 255) / 256), dim3(256), 0, stream, lw, bt);

  int nblk3 = (BTOT + SPB - 1) / SPB;   // 1829
  hipLaunchKernelGGL(k3_fused, dim3(nblk3), dim3(256), 0, stream, yws, ss, bt, lbias, out);
}

// Round 5
// 81.463 us; speedup vs baseline: 17.7538x; 1.3446x over previous
//
#include <hip/hip_runtime.h>
#include <hip/hip_bf16.h>

typedef unsigned short u16;
typedef __attribute__((ext_vector_type(8))) short short8;
typedef __attribute__((ext_vector_type(4))) float f32x4;

#define N_    16
#define C_    64
#define J_    25
#define T_    128
#define L_    9
#define SIC   8
#define OUT_  64
#define BTOT  (N_*J_*T_)      // 51200 streams
#define CNT   (BTOT*L_)       // 460800 positions
#define KPAD  896             // 9 slabs * 96 + 32 pad; 28 K-steps of 32
#define SPB   28              // streams per block (M-tile 32, rows 28..31 zero)

#define K1_BLOCKS 512
#define K1_ACT    225         // active threads/block, each does 4 positions

// ws float offsets
#define PART_OFF  0           // 512*16 = 8192 floats
#define PART2_OFF 16384       // 512 floats
#define SS_OFF    32768
#define BT_OFF    40960       // 64*896 u16 = 28672 floats
#define Y_OFF     69632       // BTOT*72 floats
#define WS_NEED   ((size_t)(Y_OFF + BTOT*72) * 4)

__device__ __forceinline__ short to_bf16(float x) {
  union { __hip_bfloat16 h; u16 u; } cv;
  cv.h = __float2bfloat16(x);
  return (short)cv.u;
}

// ---------------- Kernel 1: 1x1 conv + ReLU + BN partial stats ----------------
// 4 consecutive positions per thread (never cross an n- or j-boundary since
// 1152 % 4 == 0), float4 x loads, 128B-contiguous y stores.
__global__ __launch_bounds__(256) void k1_conv(
    const float* __restrict__ x, const float* __restrict__ cw,
    const float* __restrict__ cb, float* __restrict__ yws,
    float* __restrict__ part) {
  __shared__ float wl[SIC * C_];
  __shared__ float bl[SIC];
  __shared__ float wsum[4][16];
  int tid = threadIdx.x;
  wl[tid] = cw[tid];
  wl[tid + 256] = cw[tid + 256];
  if (tid < SIC) bl[tid] = cb[tid];
  __syncthreads();

  float vals[16];
#pragma unroll
  for (int q = 0; q < 16; q++) vals[q] = 0.f;

  if (tid < K1_ACT) {
    int p0 = (blockIdx.x * K1_ACT + tid) * 4;
    int n = p0 / 28800, rem = p0 % 28800;
    int jj = rem / 1152, tl0 = rem % 1152;
    const float* xp = x + (size_t)(n * 1600 + jj) * 1152 + tl0;

    float acc[4][8];
#pragma unroll
    for (int p = 0; p < 4; p++)
#pragma unroll
      for (int o = 0; o < 8; o++) acc[p][o] = bl[o];

#pragma unroll 8
    for (int c = 0; c < C_; c++) {
      float4 xv = *(const float4*)(xp + (size_t)c * 28800);
#pragma unroll
      for (int o = 0; o < 8; o++) {
        float wv = wl[o * C_ + c];
        acc[0][o] = fmaf(xv.x, wv, acc[0][o]);
        acc[1][o] = fmaf(xv.y, wv, acc[1][o]);
        acc[2][o] = fmaf(xv.z, wv, acc[2][o]);
        acc[3][o] = fmaf(xv.w, wv, acc[3][o]);
      }
    }
    float4* dst = (float4*)(yws + (size_t)p0 * 8);   // y addr = pos*8 floats
#pragma unroll
    for (int p = 0; p < 4; p++) {
#pragma unroll
      for (int o = 0; o < 8; o++) acc[p][o] = fmaxf(acc[p][o], 0.f);
      dst[p * 2]     = make_float4(acc[p][0], acc[p][1], acc[p][2], acc[p][3]);
      dst[p * 2 + 1] = make_float4(acc[p][4], acc[p][5], acc[p][6], acc[p][7]);
#pragma unroll
      for (int o = 0; o < 8; o++) {
        vals[o] += acc[p][o];
        vals[8 + o] += acc[p][o] * acc[p][o];
      }
    }
  }

  int lane = tid & 63, wid = tid >> 6;
#pragma unroll
  for (int v = 0; v < 16; v++) {
    float s = vals[v];
    for (int off = 32; off > 0; off >>= 1) s += __shfl_down(s, off, 64);
    if (lane == 0) wsum[wid][v] = s;
  }
  __syncthreads();
  if (tid < 16)
    part[blockIdx.x * 16 + tid] = wsum[0][tid] + wsum[1][tid] + wsum[2][tid] + wsum[3][tid];
}

// ---------------- Kernel 2a-1: reduce 512 partial rows -> 32 ----------------
__global__ __launch_bounds__(256) void k2_red1(
    const float* __restrict__ part, float* __restrict__ part2) {
  __shared__ float red[16][16];
  int tid = threadIdx.x;
  int val = tid & 15, grp = tid >> 4;
  red[grp][val] = part[(blockIdx.x * 16 + grp) * 16 + val];
  __syncthreads();
  if (tid < 16) {
    float tot = 0.f;
#pragma unroll
    for (int g = 0; g < 16; g++) tot += red[g][tid];
    part2[blockIdx.x * 16 + tid] = tot;
  }
}

// ---------------- Kernel 2a-2: finalize BN scale/shift from 32 rows ----------------
__global__ __launch_bounds__(256) void k2_stats2(
    const float* __restrict__ part2, const float* __restrict__ gamma,
    const float* __restrict__ beta, float* __restrict__ ss) {
  __shared__ float red[16][16];
  int tid = threadIdx.x;
  int val = tid & 15, grp = tid >> 4;
  red[grp][val] = part2[grp * 16 + val] + part2[(grp + 16) * 16 + val];
  __syncthreads();
  if (tid < 16) {
    float tot = 0.f;
#pragma unroll
    for (int g = 0; g < 16; g++) tot += red[g][tid];
    red[0][tid] = tot;
  }
  __syncthreads();
  if (tid < 8) {
    float mean = red[0][tid] * (1.f / CNT);
    float var  = red[0][8 + tid] * (1.f / CNT) - mean * mean;
    float sc = gamma[tid] * rsqrtf(var + 1e-5f);
    ss[tid] = sc;
    ss[8 + tid] = beta[tid] - mean * sc;
  }
}

// ---------------- Kernel 2b: lin_w -> Bt bf16 [64][896], K-permuted slab layout ----
__global__ __launch_bounds__(256) void k2_bt(
    const float* __restrict__ lw, u16* __restrict__ Bt) {
  int idx = blockIdx.x * 256 + threadIdx.x;
  if (idx >= OUT_ * KPAD) return;
  int o = idx / KPAD, k = idx % KPAD;
  float v = 0.f;
  if (k < 864) {
    int i = k / 96, p = k % 96;
    if (p < 91) {
      int orig = (p == 0) ? i : (p < 10 ? 9 + i * 9 + (p - 1) : 90 + i * 81 + (p - 10));
      v = lw[o * 819 + orig];
    }
  }
  Bt[idx] = (u16)to_bf16(v);
}

// ---------------- Kernel 3: fused BN-affine + signature + GEMM ----------------
__global__ __launch_bounds__(256, 2) void k3_fused(
    const float* __restrict__ yws, const float* __restrict__ ss,
    const u16* __restrict__ Bt, const float* __restrict__ lb,
    float* __restrict__ out) {
  __shared__ __align__(16) u16 sig_lds[32 * KPAD];   // 57,344 B
  __shared__ __align__(16) float ylds[SPB * 72];     // 8,064 B
  __shared__ float ssl[16];
  __shared__ float lbl[64];
  int tid = threadIdx.x;
  if (tid < 16) ssl[tid] = ss[tid];
  if (tid >= 64 && tid < 128) lbl[tid - 64] = lb[tid - 64];
  int gBase = blockIdx.x * SPB;
  int valid = BTOT - gBase; if (valid > SPB) valid = SPB;
  __syncthreads();

  // ----- Phase A: stage BN-affined stream points into LDS (coalesced) -----
  if (tid < SPB * 9) {
    int s = tid / 9;
    if (s < valid) {
      const float4* src = (const float4*)(yws + (size_t)gBase * 72 + (size_t)tid * 8);
      float4 a = src[0], b = src[1];
      float* drow = ylds + tid * 8;
      drow[0] = fmaf(a.x, ssl[0], ssl[8]);
      drow[1] = fmaf(a.y, ssl[1], ssl[9]);
      drow[2] = fmaf(a.z, ssl[2], ssl[10]);
      drow[3] = fmaf(a.w, ssl[3], ssl[11]);
      drow[4] = fmaf(b.x, ssl[4], ssl[12]);
      drow[5] = fmaf(b.y, ssl[5], ssl[13]);
      drow[6] = fmaf(b.z, ssl[6], ssl[14]);
      drow[7] = fmaf(b.w, ssl[7], ssl[15]);
    }
  }
  __syncthreads();

  // ----- Phase B: signature, 9 lanes per stream; vi via dynamic LDS read -----
  int s = tid / 9, i = tid % 9;
  bool act = (tid < SPB * 9) && (s < valid);
  if (act) {
    const float* yrow = ylds + s * 72;
    int i1 = (i == 0) ? 0 : (i - 1);
    float s1 = 0.f, s2[9], s3[81], prev[8], prevvi = 0.f;
#pragma unroll
    for (int jj = 0; jj < 9; jj++) s2[jj] = 0.f;
#pragma unroll
    for (int q = 0; q < 81; q++) s3[q] = 0.f;
#pragma unroll
    for (int c = 0; c < 8; c++) prev[c] = 0.f;

#pragma unroll 3
    for (int l = 0; l < 9; l++) {
      float4 a4 = *(const float4*)(yrow + l * 8);
      float4 b4 = *(const float4*)(yrow + l * 8 + 4);
      float ldsv = yrow[l * 8 + i1];               // dynamic LDS index: cheap
      float cur[8] = {a4.x, a4.y, a4.z, a4.w, b4.x, b4.y, b4.z, b4.w};
      float v[9];
      v[0] = (l == 0) ? 0.f : 0.125f;
#pragma unroll
      for (int c = 0; c < 8; c++) v[c + 1] = cur[c] - prev[c];   // prev=0 at l=0
      float curvi = (i == 0) ? (float)l * 0.125f : ldsv;
      float vi = curvi - prevvi;
      prevvi = curvi;
      float aa = fmaf(vi, (1.f / 6.f), 0.5f * s1);
      float b2 = fmaf(vi, 0.5f, s1);
#pragma unroll
      for (int jj = 0; jj < 9; jj++) {
        float tj = fmaf(aa, v[jj], s2[jj]);
#pragma unroll
        for (int k = 0; k < 9; k++) s3[jj * 9 + k] = fmaf(tj, v[k], s3[jj * 9 + k]);
        s2[jj] = fmaf(b2, v[jj], s2[jj]);
      }
      s1 += vi;
#pragma unroll
      for (int c = 0; c < 8; c++) prev[c] = cur[c];
    }

    // emit slab as 12 swizzled ds_write_b128 (slot' = slot ^ (s&7))
    u16* rowbase = sig_lds + s * KPAD;
    int sw = s & 7;
    {
      short8 ch;
      ch[0] = to_bf16(s1);
#pragma unroll
      for (int w = 0; w < 7; w++) ch[w + 1] = to_bf16(s2[w]);
      *(short8*)&rowbase[(((i * 12 + 0) ^ sw) * 8)] = ch;
    }
    {
      short8 ch;
      ch[0] = to_bf16(s2[7]); ch[1] = to_bf16(s2[8]);
#pragma unroll
      for (int w = 0; w < 6; w++) ch[w + 2] = to_bf16(s3[w]);
      *(short8*)&rowbase[(((i * 12 + 1) ^ sw) * 8)] = ch;
    }
#pragma unroll
    for (int c = 2; c <= 10; c++) {
      short8 ch;
#pragma unroll
      for (int w = 0; w < 8; w++) ch[w] = to_bf16(s3[c * 8 - 10 + w]);
      *(short8*)&rowbase[(((i * 12 + c) ^ sw) * 8)] = ch;
    }
    {
      short8 ch;
      ch[0] = to_bf16(s3[78]); ch[1] = to_bf16(s3[79]); ch[2] = to_bf16(s3[80]);
      ch[3] = 0; ch[4] = 0; ch[5] = 0; ch[6] = 0; ch[7] = 0;
      *(short8*)&rowbase[(((i * 12 + 11) ^ sw) * 8)] = ch;
    }
    // chunks 108..111 are read by the GEMM but not produced: zero them (NaN fix)
    if (i < 4) {
      short8 z = {0, 0, 0, 0, 0, 0, 0, 0};
      *(short8*)&rowbase[(((108 + i) ^ sw) * 8)] = z;
    }
  }
  // zero pad rows [valid, 32)
  {
    short8 z = {0, 0, 0, 0, 0, 0, 0, 0};
    int padChunks = (32 - valid) * 112;
    for (int e = tid; e < padChunks; e += 256) {
      int r = valid + e / 112, sl = e % 112;
      *(short8*)&sig_lds[r * KPAD + sl * 8] = z;
    }
  }
  __syncthreads();

  // ----- Phase C: GEMM M=32 x N=64 x K=896 -----
  int w = tid >> 6, l = tid & 63;
  int brow = (w << 4) + (l & 15);
  const short8* bp = (const short8*)(Bt + (size_t)brow * KPAD);
  int arow0 = (l & 15), arow1 = 16 + (l & 15);
  int asw = arow0 & 7;
  f32x4 acc0 = {0, 0, 0, 0}, acc1 = {0, 0, 0, 0};
#pragma unroll
  for (int ks = 0; ks < 28; ks++) {
    int s4 = ks * 4 + (l >> 4);
    short8 bfrag = bp[s4];
    short8 a0 = *(const short8*)&sig_lds[arow0 * KPAD + ((s4 ^ asw) * 8)];
    short8 a1 = *(const short8*)&sig_lds[arow1 * KPAD + ((s4 ^ asw) * 8)];
    acc0 = __builtin_amdgcn_mfma_f32_16x16x32_bf16(a0, bfrag, acc0, 0, 0, 0);
    acc1 = __builtin_amdgcn_mfma_f32_16x16x32_bf16(a1, bfrag, acc1, 0, 0, 0);
  }
  __syncthreads();

  // ----- Epilogue: transpose via LDS (stride 33), coalesced writeout -----
  float* c_lds = (float*)sig_lds;
  int o = (w << 4) + (l & 15);
#pragma unroll
  for (int r = 0; r < 4; r++) {
    int m0 = (l >> 4) * 4 + r;
    c_lds[o * 33 + m0] = acc0[r];
    c_lds[o * 33 + 16 + m0] = acc1[r];
  }
  __syncthreads();
  for (int e = tid; e < 2048; e += 256) {
    int o2 = e >> 5, m = e & 31;
    if (m < valid) {
      int b = gBase + m;
      int n = b / (J_ * T_), rem = b % (J_ * T_);
      int j = rem >> 7, t = rem & (T_ - 1);
      out[(((size_t)n * OUT_ + o2) * J_ + j) * T_ + t] = c_lds[o2 * 33 + m] + lbl[o2];
    }
  }
}

extern "C" void kernel_launch(void* const* d_in, const int* in_sizes, int n_in,
                              void* d_out, int out_size, void* d_ws, size_t ws_size,
                              hipStream_t stream) {
  const float* x     = (const float*)d_in[0];
  const float* cw    = (const float*)d_in[1];
  const float* cb    = (const float*)d_in[2];
  const float* gamma = (const float*)d_in[3];
  const float* beta  = (const float*)d_in[4];
  const float* lw    = (const float*)d_in[5];
  const float* lbias = (const float*)d_in[6];
  float* out = (float*)d_out;
  float* ws  = (float*)d_ws;
  if (ws_size < WS_NEED) return;

  float* part  = ws + PART_OFF;
  float* part2 = ws + PART2_OFF;
  float* ss    = ws + SS_OFF;
  u16*   bt    = (u16*)(ws + BT_OFF);
  float* yws   = ws + Y_OFF;

  hipLaunchKernelGGL(k2_bt, dim3((OUT_ * KPAD + 255) / 256), dim3(256), 0, stream, lw, bt);
  hipLaunchKernelGGL(k1_conv, dim3(K1_BLOCKS), dim3(256), 0, stream, x, cw, cb, yws, part);
  hipLaunchKernelGGL(k2_red1, dim3(32), dim3(256), 0, stream, part, part2);
  hipLaunchKernelGGL(k2_stats2, dim3(1), dim3(256), 0, stream, part2, gamma, beta, ss);

  int nblk3 = (BTOT + SPB - 1) / SPB;   // 1829
  hipLaunchKernelGGL(k3_fused, dim3(nblk3), dim3(256), 0, stream, yws, ss, bt, lbias, out);
}

// Round 6
// 70.815 us; speedup vs baseline: 20.4232x; 1.1504x over previous
//
#include <hip/hip_runtime.h>
#include <hip/hip_bf16.h>

typedef unsigned short u16;
typedef __attribute__((ext_vector_type(8))) short short8;
typedef __attribute__((ext_vector_type(4))) float f32x4;

#define N_    16
#define C_    64
#define J_    25
#define T_    128
#define L_    9
#define SIC   8
#define OUT_  64
#define BTOT  (N_*J_*T_)      // 51200 streams
#define CNT   (BTOT*L_)       // 460800 positions
#define KPAD  896             // physical row stride (112 chunks); 108 real chunks
#define NKS   27              // 27 K-steps of 32 = 864 real K
#define SPB   28              // streams per block

#define K1C_BLOCKS 900        // conv blocks: 2 positions/thread
#define K1BT_BLOCKS 224       // bt blocks: 224*256 = 57344 = 64*896
#define BT_ELEMS (OUT_*KPAD)  // 57344

// ws float offsets
#define PART_OFF  0           // 900*16 = 14400 floats
#define SS_OFF    16384
#define BT_OFF    32768       // 57344 u16 = 28672 floats
#define Y_OFF     65536       // BTOT*72 floats
#define WS_NEED   ((size_t)(Y_OFF + BTOT*72) * 4)

__device__ __forceinline__ short to_bf16(float x) {
  union { __hip_bfloat16 h; u16 u; } cv;
  cv.h = __float2bfloat16(x);
  return (short)cv.u;
}

// ------ Kernel 1: conv+ReLU+BN partials (blocks <900) | Bt rearrange (rest) ------
__global__ __launch_bounds__(256) void k1_conv(
    const float* __restrict__ x, const float* __restrict__ cw,
    const float* __restrict__ cb, const float* __restrict__ lw,
    float* __restrict__ yws, float* __restrict__ part, u16* __restrict__ Bt) {
  int tid = threadIdx.x;

  if (blockIdx.x >= K1C_BLOCKS) {
    // ---- Bt rearrange: lin_w -> bf16 [64][896], K-permuted slab layout ----
    int idx = (blockIdx.x - K1C_BLOCKS) * 256 + tid;
    if (idx < BT_ELEMS) {
      int o = idx / KPAD, k = idx % KPAD;
      float v = 0.f;
      if (k < 864) {
        int i = k / 96, p = k % 96;
        if (p < 91) {
          int orig = (p == 0) ? i : (p < 10 ? 9 + i * 9 + (p - 1) : 90 + i * 81 + (p - 10));
          v = lw[o * 819 + orig];
        }
      }
      Bt[idx] = (u16)to_bf16(v);
    }
    return;
  }

  __shared__ float wlT[C_ * SIC];   // transposed: wlT[c*8+o]
  __shared__ float bl[SIC];
  __shared__ float wsum[4][16];
  // stage transposed weights (one-time strided read, tiny)
  wlT[tid] = cw[(tid & 7) * C_ + (tid >> 3)];
  wlT[tid + 256] = cw[(tid & 7) * C_ + ((tid + 256) >> 3)];
  if (tid < SIC) bl[tid] = cb[tid];
  __syncthreads();

  int p0 = (blockIdx.x * 256 + tid) * 2;   // 2 consecutive positions, 1152%2==0
  int n = p0 / 28800, rem = p0 % 28800;
  int jj = rem / 1152, tl0 = rem % 1152;
  const float* xp = x + (size_t)(n * 1600 + jj) * 1152 + tl0;

  float acc[2][8];
#pragma unroll
  for (int p = 0; p < 2; p++)
#pragma unroll
    for (int o = 0; o < 8; o++) acc[p][o] = bl[o];

#pragma unroll 8
  for (int c = 0; c < C_; c++) {
    float2 xv = *(const float2*)(xp + (size_t)c * 28800);
    float4 w0 = *(const float4*)&wlT[c * 8];
    float4 w1 = *(const float4*)&wlT[c * 8 + 4];
    acc[0][0] = fmaf(xv.x, w0.x, acc[0][0]); acc[1][0] = fmaf(xv.y, w0.x, acc[1][0]);
    acc[0][1] = fmaf(xv.x, w0.y, acc[0][1]); acc[1][1] = fmaf(xv.y, w0.y, acc[1][1]);
    acc[0][2] = fmaf(xv.x, w0.z, acc[0][2]); acc[1][2] = fmaf(xv.y, w0.z, acc[1][2]);
    acc[0][3] = fmaf(xv.x, w0.w, acc[0][3]); acc[1][3] = fmaf(xv.y, w0.w, acc[1][3]);
    acc[0][4] = fmaf(xv.x, w1.x, acc[0][4]); acc[1][4] = fmaf(xv.y, w1.x, acc[1][4]);
    acc[0][5] = fmaf(xv.x, w1.y, acc[0][5]); acc[1][5] = fmaf(xv.y, w1.y, acc[1][5]);
    acc[0][6] = fmaf(xv.x, w1.z, acc[0][6]); acc[1][6] = fmaf(xv.y, w1.z, acc[1][6]);
    acc[0][7] = fmaf(xv.x, w1.w, acc[0][7]); acc[1][7] = fmaf(xv.y, w1.w, acc[1][7]);
  }

  float vals[16];
#pragma unroll
  for (int q = 0; q < 16; q++) vals[q] = 0.f;
  float4* dst = (float4*)(yws + (size_t)p0 * 8);
#pragma unroll
  for (int p = 0; p < 2; p++) {
#pragma unroll
    for (int o = 0; o < 8; o++) acc[p][o] = fmaxf(acc[p][o], 0.f);
    dst[p * 2]     = make_float4(acc[p][0], acc[p][1], acc[p][2], acc[p][3]);
    dst[p * 2 + 1] = make_float4(acc[p][4], acc[p][5], acc[p][6], acc[p][7]);
#pragma unroll
    for (int o = 0; o < 8; o++) {
      vals[o] += acc[p][o];
      vals[8 + o] += acc[p][o] * acc[p][o];
    }
  }

  int lane = tid & 63, wid = tid >> 6;
#pragma unroll
  for (int v = 0; v < 16; v++) {
    float s = vals[v];
    for (int off = 32; off > 0; off >>= 1) s += __shfl_down(s, off, 64);
    if (lane == 0) wsum[wid][v] = s;
  }
  __syncthreads();
  if (tid < 16)
    part[blockIdx.x * 16 + tid] = wsum[0][tid] + wsum[1][tid] + wsum[2][tid] + wsum[3][tid];
}

// ------ Kernel 2: single-block BN stats finalize (900 partial rows) ------
__global__ __launch_bounds__(256) void k2_stats(
    const float* __restrict__ part, const float* __restrict__ gamma,
    const float* __restrict__ beta, float* __restrict__ ss) {
  __shared__ float red[16][16];
  int tid = threadIdx.x;
  int val = tid & 15, grp = tid >> 4;
  float s0 = 0.f, s1 = 0.f, s2 = 0.f, s3 = 0.f;
  int b = grp;
  for (; b + 48 < K1C_BLOCKS; b += 64) {
    s0 += part[b * 16 + val];
    s1 += part[(b + 16) * 16 + val];
    s2 += part[(b + 32) * 16 + val];
    s3 += part[(b + 48) * 16 + val];
  }
  for (; b < K1C_BLOCKS; b += 16) s0 += part[b * 16 + val];
  red[grp][val] = (s0 + s1) + (s2 + s3);
  __syncthreads();
  if (tid < 16) {
    float tot = 0.f;
#pragma unroll
    for (int g = 0; g < 16; g++) tot += red[g][tid];
    red[0][tid] = tot;
  }
  __syncthreads();
  if (tid < 8) {
    float mean = red[0][tid] * (1.f / CNT);
    float var  = red[0][8 + tid] * (1.f / CNT) - mean * mean;
    float sc = gamma[tid] * rsqrtf(var + 1e-5f);
    ss[tid] = sc;
    ss[8 + tid] = beta[tid] - mean * sc;
  }
}

// ------ Kernel 3: fused BN-affine + signature + GEMM (29-row LDS, 3 blocks/CU) ------
__global__ __launch_bounds__(256, 3) void k3_fused(
    const float* __restrict__ yws, const float* __restrict__ ss,
    const u16* __restrict__ Bt, const float* __restrict__ lb,
    float* __restrict__ out) {
  __shared__ __align__(16) u16 sig_lds[29 * KPAD];   // 51,968 B; row 28 = zero row
  __shared__ float ssl[16];
  __shared__ float lbl[64];
  float* ylds = (float*)sig_lds;                     // overlay: first 8,064 B
  int tid = threadIdx.x;
  if (tid < 16) ssl[tid] = ss[tid];
  if (tid >= 64 && tid < 128) lbl[tid - 64] = lb[tid - 64];
  int gBase = blockIdx.x * SPB;
  int valid = BTOT - gBase; if (valid > SPB) valid = SPB;
  __syncthreads();

  // Phase A: stage BN-affined y into overlay; zero pad rows [valid,29)
  if (tid < SPB * 9) {
    int s = tid / 9;
    if (s < valid) {
      const float4* src = (const float4*)(yws + (size_t)gBase * 72 + (size_t)tid * 8);
      float4 a = src[0], b = src[1];
      float* drow = ylds + tid * 8;
      drow[0] = fmaf(a.x, ssl[0], ssl[8]);
      drow[1] = fmaf(a.y, ssl[1], ssl[9]);
      drow[2] = fmaf(a.z, ssl[2], ssl[10]);
      drow[3] = fmaf(a.w, ssl[3], ssl[11]);
      drow[4] = fmaf(b.x, ssl[4], ssl[12]);
      drow[5] = fmaf(b.y, ssl[5], ssl[13]);
      drow[6] = fmaf(b.z, ssl[6], ssl[14]);
      drow[7] = fmaf(b.w, ssl[7], ssl[15]);
    }
  }
  {
    // rows [valid,29) zeroed; valid>=16 always, so region (byte>=16*1792) never
    // overlaps the ylds overlay (first 8,064 B)
    short8 z = {0, 0, 0, 0, 0, 0, 0, 0};
    int padChunks = (29 - valid) * 112;
    for (int e = tid; e < padChunks; e += 256) {
      int r = valid + e / 112, sl = e % 112;
      *(short8*)&sig_lds[r * KPAD + sl * 8] = z;
    }
  }
  __syncthreads();

  // Phase B: signature state in registers (reads ylds; writes AFTER barrier)
  int s = tid / 9, i = tid % 9;
  bool act = (tid < SPB * 9) && (s < valid);
  float s1 = 0.f, s2[9], s3[81];
#pragma unroll
  for (int jj = 0; jj < 9; jj++) s2[jj] = 0.f;
#pragma unroll
  for (int q = 0; q < 81; q++) s3[q] = 0.f;
  if (act) {
    const float* yrow = ylds + s * 72;
    int i1 = (i == 0) ? 0 : (i - 1);
    float prev[8], prevvi = 0.f;
#pragma unroll
    for (int c = 0; c < 8; c++) prev[c] = 0.f;

#pragma unroll 3
    for (int l = 0; l < 9; l++) {
      float4 a4 = *(const float4*)(yrow + l * 8);
      float4 b4 = *(const float4*)(yrow + l * 8 + 4);
      float ldsv = yrow[l * 8 + i1];
      float cur[8] = {a4.x, a4.y, a4.z, a4.w, b4.x, b4.y, b4.z, b4.w};
      float v[9];
      v[0] = (l == 0) ? 0.f : 0.125f;
#pragma unroll
      for (int c = 0; c < 8; c++) v[c + 1] = cur[c] - prev[c];
      float curvi = (i == 0) ? (float)l * 0.125f : ldsv;
      float vi = curvi - prevvi;
      prevvi = curvi;
      float aa = fmaf(vi, (1.f / 6.f), 0.5f * s1);
      float b2 = fmaf(vi, 0.5f, s1);
#pragma unroll
      for (int jj = 0; jj < 9; jj++) {
        float tj = fmaf(aa, v[jj], s2[jj]);
#pragma unroll
        for (int k = 0; k < 9; k++) s3[jj * 9 + k] = fmaf(tj, v[k], s3[jj * 9 + k]);
        s2[jj] = fmaf(b2, v[jj], s2[jj]);
      }
      s1 += vi;
#pragma unroll
      for (int c = 0; c < 8; c++) prev[c] = cur[c];
    }
  }
  __syncthreads();   // all ylds reads complete before slab writes clobber overlay

  if (act) {
    // emit slab as 12 swizzled ds_write_b128 (physical slot = logical ^ (s&7))
    u16* rowbase = sig_lds + s * KPAD;
    int sw = s & 7;
    {
      short8 ch;
      ch[0] = to_bf16(s1);
#pragma unroll
      for (int w = 0; w < 7; w++) ch[w + 1] = to_bf16(s2[w]);
      *(short8*)&rowbase[(((i * 12 + 0) ^ sw) * 8)] = ch;
    }
    {
      short8 ch;
      ch[0] = to_bf16(s2[7]); ch[1] = to_bf16(s2[8]);
#pragma unroll
      for (int w = 0; w < 6; w++) ch[w + 2] = to_bf16(s3[w]);
      *(short8*)&rowbase[(((i * 12 + 1) ^ sw) * 8)] = ch;
    }
#pragma unroll
    for (int c = 2; c <= 10; c++) {
      short8 ch;
#pragma unroll
      for (int w = 0; w < 8; w++) ch[w] = to_bf16(s3[c * 8 - 10 + w]);
      *(short8*)&rowbase[(((i * 12 + c) ^ sw) * 8)] = ch;
    }
    {
      short8 ch;
      ch[0] = to_bf16(s3[78]); ch[1] = to_bf16(s3[79]); ch[2] = to_bf16(s3[80]);
      ch[3] = 0; ch[4] = 0; ch[5] = 0; ch[6] = 0; ch[7] = 0;
      *(short8*)&rowbase[(((i * 12 + 11) ^ sw) * 8)] = ch;
    }
  }
  __syncthreads();

  // Phase C: GEMM M=32 x N=64 x K=864 (27 K-steps; logical chunks 0..107)
  int w = tid >> 6, l = tid & 63;
  int brow = (w << 4) + (l & 15);
  const short8* bp = (const short8*)(Bt + (size_t)brow * KPAD);
  int arow0 = (l & 15);
  int arow1 = 16 + (l & 15); if (arow1 > 28) arow1 = 28;   // rows 29..31 -> zero row
  int asw0 = arow0 & 7, asw1 = arow1 & 7;
  f32x4 acc0 = {0, 0, 0, 0}, acc1 = {0, 0, 0, 0};
#pragma unroll
  for (int ks = 0; ks < NKS; ks++) {
    int s4 = ks * 4 + (l >> 4);
    short8 bfrag = bp[s4];
    short8 a0 = *(const short8*)&sig_lds[arow0 * KPAD + ((s4 ^ asw0) * 8)];
    short8 a1 = *(const short8*)&sig_lds[arow1 * KPAD + ((s4 ^ asw1) * 8)];
    acc0 = __builtin_amdgcn_mfma_f32_16x16x32_bf16(a0, bfrag, acc0, 0, 0, 0);
    acc1 = __builtin_amdgcn_mfma_f32_16x16x32_bf16(a1, bfrag, acc1, 0, 0, 0);
  }
  __syncthreads();

  // Epilogue: transpose via LDS (stride 33), coalesced writeout
  float* c_lds = (float*)sig_lds;
  int o = (w << 4) + (l & 15);
#pragma unroll
  for (int r = 0; r < 4; r++) {
    int m0 = (l >> 4) * 4 + r;
    c_lds[o * 33 + m0] = acc0[r];
    c_lds[o * 33 + 16 + m0] = acc1[r];
  }
  __syncthreads();
  for (int e = tid; e < 2048; e += 256) {
    int o2 = e >> 5, m = e & 31;
    if (m < valid) {
      int b = gBase + m;
      int n = b / (J_ * T_), rem = b % (J_ * T_);
      int j = rem >> 7, t = rem & (T_ - 1);
      out[(((size_t)n * OUT_ + o2) * J_ + j) * T_ + t] = c_lds[o2 * 33 + m] + lbl[o2];
    }
  }
}

extern "C" void kernel_launch(void* const* d_in, const int* in_sizes, int n_in,
                              void* d_out, int out_size, void* d_ws, size_t ws_size,
                              hipStream_t stream) {
  const float* x     = (const float*)d_in[0];
  const float* cw    = (const float*)d_in[1];
  const float* cb    = (const float*)d_in[2];
  const float* gamma = (const float*)d_in[3];
  const float* beta  = (const float*)d_in[4];
  const float* lw    = (const float*)d_in[5];
  const float* lbias = (const float*)d_in[6];
  float* out = (float*)d_out;
  float* ws  = (float*)d_ws;
  if (ws_size < WS_NEED) return;

  float* part = ws + PART_OFF;
  float* ss   = ws + SS_OFF;
  u16*   bt   = (u16*)(ws + BT_OFF);
  float* yws  = ws + Y_OFF;

  hipLaunchKernelGGL(k1_conv, dim3(K1C_BLOCKS + K1BT_BLOCKS), dim3(256), 0, stream,
                     x, cw, cb, lw, yws, part, bt);
  hipLaunchKernelGGL(k2_stats, dim3(1), dim3(256), 0, stream, part, gamma, beta, ss);

  int nblk3 = (BTOT + SPB - 1) / SPB;   // 1829
  hipLaunchKernelGGL(k3_fused, dim3(nblk3), dim3(256), 0, stream, yws, ss, bt, lbias, out);
}